// Round 6
// baseline (450.499 us; speedup 1.0000x reference)
//
#include <hip/hip_runtime.h>
#include <hip/hip_bf16.h>
#include <math.h>

// Problem constants (B,D,N from reference)
#define MDIM 4096   // batch rows
#define KDIM 2048   // feature dim D
#define NDIM 4096   // output dim N
#define DT   0.01f
#define TWO_PI_F 6.283185307179586f
#define CH 64       // scan chunks
#define CL 64       // steps per chunk  (CH*CL == MDIM)

typedef __attribute__((ext_vector_type(8))) short bf16x8;
typedef __attribute__((ext_vector_type(4))) float f32x4;

__device__ __forceinline__ unsigned short f2bf(float f) {
  unsigned int u = __float_as_uint(f);
  u += 0x7FFFu + ((u >> 16) & 1u);           // round-to-nearest-even
  return (unsigned short)(u >> 16);
}
__device__ __forceinline__ float bf2f(unsigned short u) {
  return __uint_as_float(((unsigned int)u) << 16);
}

// -------- fused cast fp32 -> bf16 for x and W (both 8M floats) --------
__global__ void cast2_bf16_kernel(const float* __restrict__ s0,
                                  unsigned short* __restrict__ d0,
                                  const float* __restrict__ s1,
                                  unsigned short* __restrict__ d1,
                                  int n4each) {
  int i = blockIdx.x * blockDim.x + threadIdx.x;
  const float4* sp;
  ushort4* dp;
  int j;
  if (i < n4each) { sp = (const float4*)s0; dp = (ushort4*)d0; j = i; }
  else            { sp = (const float4*)s1; dp = (ushort4*)d1; j = i - n4each; }
  float4 v = sp[j];
  ushort4 o;
  o.x = f2bf(v.x); o.y = f2bf(v.y); o.z = f2bf(v.z); o.w = f2bf(v.w);
  dp[j] = o;
}

// ---------------- GEMM: force = x @ W^T + b, bf16 MFMA ----------------
// 128x128 tile, BK=64, 4 waves (2x2), 4x4 grid of 16x16x32 MFMAs per wave,
// two K-steps per staged tile. LDS layout: row stride 64 shorts (128 B), with
// XOR swizzle phys_group = logical_group ^ (row&7) so that both staging
// writes and ds_read_b128 fragment reads are bank-conflict-free (row stride
// 128 B alone would put all rows on the same banks -> 8-way conflicts; this
// was the measured 8.4M SQ_LDS_BANK_CONFLICT in rounds 2-5).
__global__ __launch_bounds__(256, 2) void gemm_bt_kernel(
    const unsigned short* __restrict__ A,
    const unsigned short* __restrict__ Bm,
    const float* __restrict__ bias,
    unsigned short* __restrict__ C) {
  __shared__ __align__(16) unsigned short smem[16384];   // 32 KB
  unsigned short* sA = smem;           // [128][64]
  unsigned short* sB = smem + 8192;    // [128][64]

  const int tid  = threadIdx.x;
  const int lane = tid & 63;
  const int wave = tid >> 6;
  const int wr = wave >> 1;        // wave row (0..1) -> 64 rows
  const int wc = wave & 1;         // wave col (0..1) -> 64 cols
  const int q  = lane >> 4;        // quad 0..3
  const int lm = lane & 15;

  const int bM = blockIdx.x * 128;
  const int bN = blockIdx.y * 128;

  f32x4 acc[4][4];
#pragma unroll
  for (int i = 0; i < 4; i++)
#pragma unroll
    for (int j = 0; j < 4; j++) acc[i][j] = (f32x4){0.f, 0.f, 0.f, 0.f};

  // staging: 128x64 bf16 tile = 16KB = 1024 slots x 16B; 4 slots/thread
  const unsigned short* gA[4];
  const unsigned short* gB[4];
  int dst[4];
#pragma unroll
  for (int p = 0; p < 4; p++) {
    int slot = tid + 256 * p;          // 0..1023
    int row  = slot >> 3;              // 0..127
    int g    = slot & 7;               // logical 8-elem group
    gA[p] = A  + (size_t)(bM + row) * KDIM + g * 8;
    gB[p] = Bm + (size_t)(bN + row) * KDIM + g * 8;
    dst[p] = row * 64 + ((g ^ (row & 7)) * 8);   // swizzled store offset
  }

  // fragment read offsets (row&7 == lm&7 since wave/mt offsets are mult of 8)
  int roA[4], roB[4];
#pragma unroll
  for (int t = 0; t < 4; t++) {
    roA[t] = (wr * 64 + t * 16 + lm) * 64;
    roB[t] = (wc * 64 + t * 16 + lm) * 64;
  }
  const int swz = lm & 7;

  for (int k0 = 0; k0 < KDIM; k0 += 64) {
    uint4 av[4], bv[4];
#pragma unroll
    for (int p = 0; p < 4; p++) {
      av[p] = *(const uint4*)(gA[p] + k0);
      bv[p] = *(const uint4*)(gB[p] + k0);
    }
    __syncthreads();               // previous iter's LDS reads complete
#pragma unroll
    for (int p = 0; p < 4; p++) {
      *(uint4*)&sA[dst[p]] = av[p];
      *(uint4*)&sB[dst[p]] = bv[p];
    }
    __syncthreads();               // LDS tile visible

#pragma unroll
    for (int kk = 0; kk < 2; kk++) {
      bf16x8 af[4], bfr[4];
#pragma unroll
      for (int mt = 0; mt < 4; mt++)
        af[mt]  = *(const bf16x8*)&sA[roA[mt] + (((kk * 4 + q) ^ swz) * 8)];
#pragma unroll
      for (int nt = 0; nt < 4; nt++)
        bfr[nt] = *(const bf16x8*)&sB[roB[nt] + (((kk * 4 + q) ^ swz) * 8)];

#pragma unroll
      for (int mt = 0; mt < 4; mt++)
#pragma unroll
        for (int nt = 0; nt < 4; nt++)
          acc[mt][nt] = __builtin_amdgcn_mfma_f32_16x16x32_bf16(
              af[mt], bfr[nt], acc[mt][nt], 0, 0, 0);
    }
  }

  // epilogue: D layout col=lane&15, row=quad*4+reg (m89/m91-verified)
#pragma unroll
  for (int nt = 0; nt < 4; nt++) {
    const int col = bN + wc * 64 + nt * 16 + lm;
    const float bz = bias[col];
#pragma unroll
    for (int mt = 0; mt < 4; mt++) {
      const int row0 = bM + wr * 64 + mt * 16 + q * 4;
#pragma unroll
      for (int r = 0; r < 4; r++)
        C[(size_t)(row0 + r) * NDIM + col] = f2bf(acc[mt][nt][r] + bz);
    }
  }
}

// -------- scan pass 1: per-chunk partials (zero init), 4 cols/thread --------
__global__ void scan_pass1(const unsigned short* __restrict__ force,
                           const float* __restrict__ freq,
                           const float* __restrict__ damp,
                           float* __restrict__ chunkS,
                           float* __restrict__ chunkV) {
  int gid = blockIdx.x * blockDim.x + threadIdx.x;   // 0 .. CH*NDIM/4
  int n4 = gid & (NDIM / 4 - 1);
  int c  = gid >> 10;                                // / (NDIM/4)
  int n  = n4 * 4;
  float4 fr = *(const float4*)&freq[n];
  float4 dv = *(const float4*)&damp[n];
  float osq[4] = {TWO_PI_F * fr.x, TWO_PI_F * fr.y, TWO_PI_F * fr.z, TWO_PI_F * fr.w};
  float dp[4]  = {dv.x, dv.y, dv.z, dv.w};
  float s[4] = {0.f, 0.f, 0.f, 0.f}, v[4] = {0.f, 0.f, 0.f, 0.f};
#pragma unroll
  for (int j = 0; j < 4; j++) osq[j] *= osq[j];
  const unsigned short* fp = force + (size_t)c * CL * NDIM + n;
#pragma unroll 4
  for (int i = 0; i < CL; i++) {
    ushort4 fv = *(const ushort4*)&fp[(size_t)i * NDIM];
    float f[4] = {bf2f(fv.x), bf2f(fv.y), bf2f(fv.z), bf2f(fv.w)};
#pragma unroll
    for (int j = 0; j < 4; j++) {
      float a = -osq[j] * s[j] - dp[j] * v[j] + f[j];
      v[j] += a * DT;
      s[j] += v[j] * DT;
    }
  }
  *(float4*)&chunkS[c * NDIM + n] = (float4){s[0], s[1], s[2], s[3]};
  *(float4*)&chunkV[c * NDIM + n] = (float4){v[0], v[1], v[2], v[3]};
}

// ---------------- scan pass 2: sequential combine over chunks ----------------
__global__ void scan_pass2(const float* __restrict__ chunkS,
                           const float* __restrict__ chunkV,
                           const float* __restrict__ freq,
                           const float* __restrict__ damp,
                           float* __restrict__ carryS,
                           float* __restrict__ carryV) {
  int n = blockIdx.x * blockDim.x + threadIdx.x;     // 0..NDIM-1
  float om = TWO_PI_F * freq[n];
  float osq = om * om;
  float dp = damp[n];
  // M = [[1-osq*dt^2, dt*(1-dp*dt)], [-osq*dt, 1-dp*dt]];  compute M^64
  float a00 = 1.f - osq * DT * DT, a01 = DT * (1.f - dp * DT);
  float a10 = -osq * DT,           a11 = 1.f - dp * DT;
#pragma unroll
  for (int i = 0; i < 6; i++) {
    float b00 = a00 * a00 + a01 * a10;
    float b01 = a00 * a01 + a01 * a11;
    float b10 = a10 * a00 + a11 * a10;
    float b11 = a10 * a01 + a11 * a11;
    a00 = b00; a01 = b01; a10 = b10; a11 = b11;
  }
  float cs = 0.f, cv = 0.f;
#pragma unroll 8
  for (int c = 0; c < CH; c++) {
    carryS[c * NDIM + n] = cs;
    carryV[c * NDIM + n] = cv;
    float ls = chunkS[c * NDIM + n];
    float lv = chunkV[c * NDIM + n];
    float ns = a00 * cs + a01 * cv + ls;
    float nv = a10 * cs + a11 * cv + lv;
    cs = ns; cv = nv;
  }
}

// -------- scan pass 3: replay with carries, osc+clip, fp32 out, 4 cols ------
__global__ void scan_pass3(const unsigned short* __restrict__ force,
                           const float* __restrict__ amp,
                           const float* __restrict__ freq,
                           const float* __restrict__ phase,
                           const float* __restrict__ damp,
                           const float* __restrict__ carryS,
                           const float* __restrict__ carryV,
                           float* __restrict__ out) {
  int gid = blockIdx.x * blockDim.x + threadIdx.x;   // 0 .. CH*NDIM/4
  int n4 = gid & (NDIM / 4 - 1);
  int c  = gid >> 10;
  int n  = n4 * 4;
  float4 fr = *(const float4*)&freq[n];
  float4 dv = *(const float4*)&damp[n];
  float4 am = *(const float4*)&amp[n];
  float4 ph = *(const float4*)&phase[n];
  float om[4] = {TWO_PI_F * fr.x, TWO_PI_F * fr.y, TWO_PI_F * fr.z, TWO_PI_F * fr.w};
  float dp[4] = {dv.x, dv.y, dv.z, dv.w};
  float osq[4], osc[4], s[4], v[4];
  float amv[4] = {am.x, am.y, am.z, am.w};
  float phv[4] = {ph.x, ph.y, ph.z, ph.w};
#pragma unroll
  for (int j = 0; j < 4; j++) {
    osq[j] = om[j] * om[j];
    osc[j] = amv[j] * sinf(om[j] * DT + phv[j]);     // t = DT
  }
  float4 csv = *(const float4*)&carryS[c * NDIM + n];
  float4 cvv = *(const float4*)&carryV[c * NDIM + n];
  s[0] = csv.x; s[1] = csv.y; s[2] = csv.z; s[3] = csv.w;
  v[0] = cvv.x; v[1] = cvv.y; v[2] = cvv.z; v[3] = cvv.w;
  const unsigned short* fp = force + (size_t)c * CL * NDIM + n;
  float* op = out + (size_t)c * CL * NDIM + n;
#pragma unroll 4
  for (int i = 0; i < CL; i++) {
    ushort4 fv = *(const ushort4*)&fp[(size_t)i * NDIM];
    float f[4] = {bf2f(fv.x), bf2f(fv.y), bf2f(fv.z), bf2f(fv.w)};
    float o[4];
#pragma unroll
    for (int j = 0; j < 4; j++) {
      float a = -osq[j] * s[j] - dp[j] * v[j] + f[j];
      v[j] += a * DT;
      s[j] += v[j] * DT;
      o[j] = fminf(1.f, fmaxf(-1.f, s[j] + osc[j]));
    }
    *(float4*)&op[(size_t)i * NDIM] = (float4){o[0], o[1], o[2], o[3]};
  }
}

// ---------------- launch ----------------
extern "C" void kernel_launch(void* const* d_in, const int* in_sizes, int n_in,
                              void* d_out, int out_size, void* d_ws, size_t ws_size,
                              hipStream_t stream) {
  const float* x     = (const float*)d_in[0];
  const float* W     = (const float*)d_in[1];
  const float* bias  = (const float*)d_in[2];
  const float* amp   = (const float*)d_in[3];
  const float* freq  = (const float*)d_in[4];
  const float* phase = (const float*)d_in[5];
  const float* damp  = (const float*)d_in[6];

  // workspace layout (peak 64 MiB, proven safe):
  //   [0,16Mi)   xbf  (chunk/carry arrays alias this region after GEMM)
  //   [16,32Mi)  wbf
  //   [32,64Mi)  force bf16
  unsigned short* xbf   = (unsigned short*)d_ws;
  unsigned short* wbf   = xbf + (size_t)MDIM * KDIM;
  unsigned short* force = wbf + (size_t)NDIM * KDIM;
  float* chunkS = (float*)d_ws;            // aliases xbf: dead after GEMM
  float* chunkV = chunkS + CH * NDIM;
  float* carryS = chunkV + CH * NDIM;
  float* carryV = carryS + CH * NDIM;

  const int n4each = MDIM * KDIM / 4;      // == NDIM*KDIM/4 (both 8M floats)
  cast2_bf16_kernel<<<(2 * n4each + 255) / 256, 256, 0, stream>>>(
      x, xbf, W, wbf, n4each);

  dim3 gg(MDIM / 128, NDIM / 128);
  gemm_bt_kernel<<<gg, 256, 0, stream>>>(xbf, wbf, bias, force);

  scan_pass1<<<CH * NDIM / 4 / 256, 256, 0, stream>>>(force, freq, damp,
                                                      chunkS, chunkV);
  scan_pass2<<<NDIM / 256, 256, 0, stream>>>(chunkS, chunkV, freq, damp,
                                             carryS, carryV);
  scan_pass3<<<CH * NDIM / 4 / 256, 256, 0, stream>>>(
      force, amp, freq, phase, damp, carryS, carryV, (float*)d_out);
}

// Round 7
// 229.073 us; speedup vs baseline: 1.9666x; 1.9666x over previous
//
#include <hip/hip_runtime.h>
#include <hip/hip_bf16.h>
#include <math.h>

// Problem constants (B,D,N from reference)
#define MDIM 4096   // batch rows
#define KDIM 2048   // feature dim D
#define NDIM 4096   // output dim N
#define DT   0.01f
#define TWO_PI_F 6.283185307179586f
#define CH 64       // scan chunks
#define CL 64       // steps per chunk  (CH*CL == MDIM)

typedef __attribute__((ext_vector_type(8))) short bf16x8;
typedef __attribute__((ext_vector_type(4))) float f32x4;

__device__ __forceinline__ unsigned short f2bf(float f) {
  unsigned int u = __float_as_uint(f);
  u += 0x7FFFu + ((u >> 16) & 1u);           // round-to-nearest-even
  return (unsigned short)(u >> 16);
}
__device__ __forceinline__ float bf2f(unsigned short u) {
  return __uint_as_float(((unsigned int)u) << 16);
}

// -------- fused cast fp32 -> bf16 for x and W (both 8M floats) --------
__global__ void cast2_bf16_kernel(const float* __restrict__ s0,
                                  unsigned short* __restrict__ d0,
                                  const float* __restrict__ s1,
                                  unsigned short* __restrict__ d1,
                                  int n4each) {
  int i = blockIdx.x * blockDim.x + threadIdx.x;
  const float4* sp;
  ushort4* dp;
  int j;
  if (i < n4each) { sp = (const float4*)s0; dp = (ushort4*)d0; j = i; }
  else            { sp = (const float4*)s1; dp = (ushort4*)d1; j = i - n4each; }
  float4 v = sp[j];
  ushort4 o;
  o.x = f2bf(v.x); o.y = f2bf(v.y); o.z = f2bf(v.z); o.w = f2bf(v.w);
  dp[j] = o;
}

// ---------------- GEMM: force = x @ W^T + b, bf16 MFMA ----------------
// 128x128 tile, BK=32 (proven register footprint, no spill), 4 waves (2x2),
// 4x4 grid of 16x16x32 MFMAs per wave.
// LDS swizzle: within each 32-elem row, 8-elem group g is stored at physical
// group g ^ ((row>>1)&3). Fragment ds_read_b128 (quad q, rows=lm) then hits
// all 8 four-bank sets 2-way per 16-lane phase (free, m136) instead of the
// 8-way that produced 8.4M SQ_LDS_BANK_CONFLICT in rounds 2-5. Staging
// writes remain a per-row group permutation -> still 2-way (free).
__global__ __launch_bounds__(256, 2) void gemm_bt_kernel(
    const unsigned short* __restrict__ A,
    const unsigned short* __restrict__ Bm,
    const float* __restrict__ bias,
    unsigned short* __restrict__ C) {
  __shared__ __align__(16) unsigned short sA[128 * 32];
  __shared__ __align__(16) unsigned short sB[128 * 32];

  const int tid  = threadIdx.x;
  const int lane = tid & 63;
  const int wave = tid >> 6;
  const int wr = wave >> 1;        // wave row (0..1) -> 64 rows
  const int wc = wave & 1;         // wave col (0..1) -> 64 cols
  const int q  = lane >> 4;        // quad 0..3
  const int lm = lane & 15;

  const int bM = blockIdx.x * 128;
  const int bN = blockIdx.y * 128;

  f32x4 acc[4][4];
#pragma unroll
  for (int i = 0; i < 4; i++)
#pragma unroll
    for (int j = 0; j < 4; j++) acc[i][j] = (f32x4){0.f, 0.f, 0.f, 0.f};

  // staging: 128x32 bf16 tile = 8KB = 512 slots x 16B; 2 slots/thread.
  // slot -> row = slot>>2, group g = slot&3; store at swizzled group.
  const int idx0 = tid;            // rows 0..63
  const int idx1 = tid + 256;      // rows 64..127
  const int r0 = idx0 >> 2, g0 = idx0 & 3;
  const int r1 = idx1 >> 2, g1 = idx1 & 3;
  const int dst0 = r0 * 32 + ((g0 ^ ((r0 >> 1) & 3)) * 8);
  const int dst1 = r1 * 32 + ((g1 ^ ((r1 >> 1) & 3)) * 8);
  const unsigned short* gA0 = A  + (size_t)(bM + r0) * KDIM + g0 * 8;
  const unsigned short* gA1 = A  + (size_t)(bM + r1) * KDIM + g1 * 8;
  const unsigned short* gB0 = Bm + (size_t)(bN + r0) * KDIM + g0 * 8;
  const unsigned short* gB1 = Bm + (size_t)(bN + r1) * KDIM + g1 * 8;

  // fragment read: row = (wave-base)+t*16+lm; (row>>1)&3 == (lm>>1)&3 since
  // wave-base and t*16 are multiples of 16. k-group q sits at q^((lm>>1)&3).
  const int rq = (q ^ ((lm >> 1) & 3)) * 8;

  for (int k0 = 0; k0 < KDIM; k0 += 32) {
    uint4 av0 = *(const uint4*)(gA0 + k0);
    uint4 av1 = *(const uint4*)(gA1 + k0);
    uint4 bv0 = *(const uint4*)(gB0 + k0);
    uint4 bv1 = *(const uint4*)(gB1 + k0);
    __syncthreads();               // previous iter's LDS reads complete
    *(uint4*)&sA[dst0] = av0;
    *(uint4*)&sA[dst1] = av1;
    *(uint4*)&sB[dst0] = bv0;
    *(uint4*)&sB[dst1] = bv1;
    __syncthreads();               // LDS tile visible

    bf16x8 af[4], bfr[4];
#pragma unroll
    for (int mt = 0; mt < 4; mt++)
      af[mt]  = *(const bf16x8*)&sA[(wr * 64 + mt * 16 + lm) * 32 + rq];
#pragma unroll
    for (int nt = 0; nt < 4; nt++)
      bfr[nt] = *(const bf16x8*)&sB[(wc * 64 + nt * 16 + lm) * 32 + rq];

#pragma unroll
    for (int mt = 0; mt < 4; mt++)
#pragma unroll
      for (int nt = 0; nt < 4; nt++)
        acc[mt][nt] = __builtin_amdgcn_mfma_f32_16x16x32_bf16(
            af[mt], bfr[nt], acc[mt][nt], 0, 0, 0);
  }

  // epilogue: D layout col=lane&15, row=quad*4+reg (m89/m91-verified)
#pragma unroll
  for (int nt = 0; nt < 4; nt++) {
    const int col = bN + wc * 64 + nt * 16 + lm;
    const float bz = bias[col];
#pragma unroll
    for (int mt = 0; mt < 4; mt++) {
      const int row0 = bM + wr * 64 + mt * 16 + q * 4;
#pragma unroll
      for (int r = 0; r < 4; r++)
        C[(size_t)(row0 + r) * NDIM + col] = f2bf(acc[mt][nt][r] + bz);
    }
  }
}

// -------- scan pass 1: per-chunk partials (zero init), 4 cols/thread --------
__global__ void scan_pass1(const unsigned short* __restrict__ force,
                           const float* __restrict__ freq,
                           const float* __restrict__ damp,
                           float* __restrict__ chunkS,
                           float* __restrict__ chunkV) {
  int gid = blockIdx.x * blockDim.x + threadIdx.x;   // 0 .. CH*NDIM/4
  int n4 = gid & (NDIM / 4 - 1);
  int c  = gid >> 10;                                // / (NDIM/4)
  int n  = n4 * 4;
  float4 fr = *(const float4*)&freq[n];
  float4 dv = *(const float4*)&damp[n];
  float osq[4] = {TWO_PI_F * fr.x, TWO_PI_F * fr.y, TWO_PI_F * fr.z, TWO_PI_F * fr.w};
  float dp[4]  = {dv.x, dv.y, dv.z, dv.w};
  float s[4] = {0.f, 0.f, 0.f, 0.f}, v[4] = {0.f, 0.f, 0.f, 0.f};
#pragma unroll
  for (int j = 0; j < 4; j++) osq[j] *= osq[j];
  const unsigned short* fp = force + (size_t)c * CL * NDIM + n;
#pragma unroll 4
  for (int i = 0; i < CL; i++) {
    ushort4 fv = *(const ushort4*)&fp[(size_t)i * NDIM];
    float f[4] = {bf2f(fv.x), bf2f(fv.y), bf2f(fv.z), bf2f(fv.w)};
#pragma unroll
    for (int j = 0; j < 4; j++) {
      float a = -osq[j] * s[j] - dp[j] * v[j] + f[j];
      v[j] += a * DT;
      s[j] += v[j] * DT;
    }
  }
  *(float4*)&chunkS[c * NDIM + n] = (float4){s[0], s[1], s[2], s[3]};
  *(float4*)&chunkV[c * NDIM + n] = (float4){v[0], v[1], v[2], v[3]};
}

// ---------------- scan pass 2: sequential combine over chunks ----------------
__global__ void scan_pass2(const float* __restrict__ chunkS,
                           const float* __restrict__ chunkV,
                           const float* __restrict__ freq,
                           const float* __restrict__ damp,
                           float* __restrict__ carryS,
                           float* __restrict__ carryV) {
  int n = blockIdx.x * blockDim.x + threadIdx.x;     // 0..NDIM-1
  float om = TWO_PI_F * freq[n];
  float osq = om * om;
  float dp = damp[n];
  // M = [[1-osq*dt^2, dt*(1-dp*dt)], [-osq*dt, 1-dp*dt]];  compute M^64
  float a00 = 1.f - osq * DT * DT, a01 = DT * (1.f - dp * DT);
  float a10 = -osq * DT,           a11 = 1.f - dp * DT;
#pragma unroll
  for (int i = 0; i < 6; i++) {
    float b00 = a00 * a00 + a01 * a10;
    float b01 = a00 * a01 + a01 * a11;
    float b10 = a10 * a00 + a11 * a10;
    float b11 = a10 * a01 + a11 * a11;
    a00 = b00; a01 = b01; a10 = b10; a11 = b11;
  }
  float cs = 0.f, cv = 0.f;
#pragma unroll 8
  for (int c = 0; c < CH; c++) {
    carryS[c * NDIM + n] = cs;
    carryV[c * NDIM + n] = cv;
    float ls = chunkS[c * NDIM + n];
    float lv = chunkV[c * NDIM + n];
    float ns = a00 * cs + a01 * cv + ls;
    float nv = a10 * cs + a11 * cv + lv;
    cs = ns; cv = nv;
  }
}

// -------- scan pass 3: replay with carries, osc+clip, fp32 out, 4 cols ------
__global__ void scan_pass3(const unsigned short* __restrict__ force,
                           const float* __restrict__ amp,
                           const float* __restrict__ freq,
                           const float* __restrict__ phase,
                           const float* __restrict__ damp,
                           const float* __restrict__ carryS,
                           const float* __restrict__ carryV,
                           float* __restrict__ out) {
  int gid = blockIdx.x * blockDim.x + threadIdx.x;   // 0 .. CH*NDIM/4
  int n4 = gid & (NDIM / 4 - 1);
  int c  = gid >> 10;
  int n  = n4 * 4;
  float4 fr = *(const float4*)&freq[n];
  float4 dv = *(const float4*)&damp[n];
  float4 am = *(const float4*)&amp[n];
  float4 ph = *(const float4*)&phase[n];
  float om[4] = {TWO_PI_F * fr.x, TWO_PI_F * fr.y, TWO_PI_F * fr.z, TWO_PI_F * fr.w};
  float dp[4] = {dv.x, dv.y, dv.z, dv.w};
  float osq[4], osc[4], s[4], v[4];
  float amv[4] = {am.x, am.y, am.z, am.w};
  float phv[4] = {ph.x, ph.y, ph.z, ph.w};
#pragma unroll
  for (int j = 0; j < 4; j++) {
    osq[j] = om[j] * om[j];
    osc[j] = amv[j] * sinf(om[j] * DT + phv[j]);     // t = DT
  }
  float4 csv = *(const float4*)&carryS[c * NDIM + n];
  float4 cvv = *(const float4*)&carryV[c * NDIM + n];
  s[0] = csv.x; s[1] = csv.y; s[2] = csv.z; s[3] = csv.w;
  v[0] = cvv.x; v[1] = cvv.y; v[2] = cvv.z; v[3] = cvv.w;
  const unsigned short* fp = force + (size_t)c * CL * NDIM + n;
  float* op = out + (size_t)c * CL * NDIM + n;
#pragma unroll 4
  for (int i = 0; i < CL; i++) {
    ushort4 fv = *(const ushort4*)&fp[(size_t)i * NDIM];
    float f[4] = {bf2f(fv.x), bf2f(fv.y), bf2f(fv.z), bf2f(fv.w)};
    float o[4];
#pragma unroll
    for (int j = 0; j < 4; j++) {
      float a = -osq[j] * s[j] - dp[j] * v[j] + f[j];
      v[j] += a * DT;
      s[j] += v[j] * DT;
      o[j] = fminf(1.f, fmaxf(-1.f, s[j] + osc[j]));
    }
    *(float4*)&op[(size_t)i * NDIM] = (float4){o[0], o[1], o[2], o[3]};
  }
}

// ---------------- launch ----------------
extern "C" void kernel_launch(void* const* d_in, const int* in_sizes, int n_in,
                              void* d_out, int out_size, void* d_ws, size_t ws_size,
                              hipStream_t stream) {
  const float* x     = (const float*)d_in[0];
  const float* W     = (const float*)d_in[1];
  const float* bias  = (const float*)d_in[2];
  const float* amp   = (const float*)d_in[3];
  const float* freq  = (const float*)d_in[4];
  const float* phase = (const float*)d_in[5];
  const float* damp  = (const float*)d_in[6];

  // workspace layout (peak 64 MiB, proven safe):
  //   [0,16Mi)   xbf  (chunk/carry arrays alias this region after GEMM)
  //   [16,32Mi)  wbf
  //   [32,64Mi)  force bf16
  unsigned short* xbf   = (unsigned short*)d_ws;
  unsigned short* wbf   = xbf + (size_t)MDIM * KDIM;
  unsigned short* force = wbf + (size_t)NDIM * KDIM;
  float* chunkS = (float*)d_ws;            // aliases xbf: dead after GEMM
  float* chunkV = chunkS + CH * NDIM;
  float* carryS = chunkV + CH * NDIM;
  float* carryV = carryS + CH * NDIM;

  const int n4each = MDIM * KDIM / 4;      // == NDIM*KDIM/4 (both 8M floats)
  cast2_bf16_kernel<<<(2 * n4each + 255) / 256, 256, 0, stream>>>(
      x, xbf, W, wbf, n4each);

  dim3 gg(MDIM / 128, NDIM / 128);
  gemm_bt_kernel<<<gg, 256, 0, stream>>>(xbf, wbf, bias, force);

  scan_pass1<<<CH * NDIM / 4 / 256, 256, 0, stream>>>(force, freq, damp,
                                                      chunkS, chunkV);
  scan_pass2<<<NDIM / 256, 256, 0, stream>>>(chunkS, chunkV, freq, damp,
                                             carryS, carryV);
  scan_pass3<<<CH * NDIM / 4 / 256, 256, 0, stream>>>(
      force, amp, freq, phase, damp, carryS, carryV, (float*)d_out);
}